// Round 2
// baseline (1086.018 us; speedup 1.0000x reference)
//
#include <hip/hip_runtime.h>
#include <math.h>

#define LN_EPS 1e-5f

typedef float v2f  __attribute__((ext_vector_type(2)));
typedef float f32x4 __attribute__((ext_vector_type(4)));
typedef short s16x8 __attribute__((ext_vector_type(8)));   // 8 bf16 in 4 VGPRs (guide §3)

__device__ __forceinline__ v2f pf(v2f a, v2f b, v2f c) {
    return __builtin_elementwise_fma(a, b, c);
}
__device__ __forceinline__ v2f bc2(float s) { v2f r; r.x = s; r.y = s; return r; }

// fp32 -> bf16 (RNE), bf16 -> fp32
__device__ __forceinline__ short f2bf(float f) {
    union { float f; unsigned u; } v; v.f = f;
    return (short)((v.u + 0x7fffu + ((v.u >> 16) & 1u)) >> 16);
}
__device__ __forceinline__ float bf2f(short s) {
    union { unsigned u; float f; } v; v.u = ((unsigned)(unsigned short)s) << 16;
    return v.f;
}

// LayerNorm over 2*D2 values held as v2f[D2], then *g+b, then ReLU (in place).
template<int D2>
__device__ __forceinline__ void ln_relu2(v2f (&v)[D2],
                                         const float* __restrict__ g,
                                         const float* __restrict__ b) {
    const float invD = 1.0f / (float)(2 * D2);
    float m = 0.f;
#pragma unroll
    for (int i = 0; i < D2; ++i) m += v[i].x + v[i].y;
    m *= invD;
    float var = 0.f;
#pragma unroll
    for (int i = 0; i < D2; ++i) {
        float dx = v[i].x - m, dy = v[i].y - m;
        var = fmaf(dx, dx, var);
        var = fmaf(dy, dy, var);
    }
    var *= invD;
    const float rs = rsqrtf(var + LN_EPS);
    const v2f* g2 = (const v2f*)g;
    const v2f* b2 = (const v2f*)b;
#pragma unroll
    for (int i = 0; i < D2; ++i) {
        v2f t = pf((v[i] - m) * rs, g2[i], b2[i]);
        v[i].x = fmaxf(t.x, 0.f);
        v[i].y = fmaxf(t.y, 0.f);
    }
}

template<int IN2, int OUT2>
__device__ __forceinline__ void mv2(const v2f (&x)[IN2],
                                    const float* __restrict__ W,
                                    v2f (&y)[OUT2]) {
    const v2f* W2 = (const v2f*)W;
#pragma unroll
    for (int j = 0; j < OUT2; ++j) y[j] = bc2(0.f);
#pragma unroll
    for (int k2 = 0; k2 < IN2; ++k2) {
        const v2f x0 = bc2(x[k2].x), x1 = bc2(x[k2].y);
#pragma unroll
        for (int j = 0; j < OUT2; ++j) {
            y[j] = pf(x0, W2[(2 * k2) * OUT2 + j], y[j]);
            y[j] = pf(x1, W2[(2 * k2 + 1) * OUT2 + j], y[j]);
        }
    }
}

template<int IN2, int OUT2>
__device__ __forceinline__ void mv2_bias(const v2f (&x)[IN2],
                                         const float* __restrict__ W,
                                         const float* __restrict__ bias,
                                         v2f (&y)[OUT2]) {
    const v2f* W2 = (const v2f*)W;
    const v2f* b2 = (const v2f*)bias;
#pragma unroll
    for (int j = 0; j < OUT2; ++j) y[j] = b2[j];
#pragma unroll
    for (int k2 = 0; k2 < IN2; ++k2) {
        const v2f x0 = bc2(x[k2].x), x1 = bc2(x[k2].y);
#pragma unroll
        for (int j = 0; j < OUT2; ++j) {
            y[j] = pf(x0, W2[(2 * k2) * OUT2 + j], y[j]);
            y[j] = pf(x1, W2[(2 * k2 + 1) * OUT2 + j], y[j]);
        }
    }
}

// One MFMA phase: row[0..63] (this lane's row of  X[128-wide slice] @ W[128,64])
// W row-major [128][64]. Result is PRE-LayerNorm, fp32 (via bf16 LDS round-trip).
// MFMA layouts (guide §3, HW-verified m89/m91/m120):
//   A[m=lane&15][k=quad*8+j]  B[k=quad*8+j][n=lane&15]  D: col=lane&15,row=quad*4+reg
// Register-footprint shape: A-fragments resident (16 x s16x8 = 64 VGPRs,
// loaded once), B-fragments streamed per output-col-tile (4 x s16x8 = 16
// VGPRs live at a time). Peak ~84 live VGPRs in the hot region.
// NOTE (round-1 post-mortem): do NOT pin waves-per-EU via __launch_bounds__'
// second arg — (256,4) forced arch-VGPR to 64 and spilled ~1.7 GB of scratch
// traffic (hbm_bytes 0.28->2.07 GB, dur 405->760 us). Plain (256) lands at
// the 128-VGPR boundary (4 waves/SIMD) with zero spill.
__device__ __forceinline__ void mfma_phase(const float* __restrict__ rep,
                                           const float* __restrict__ W,
                                           int waveRow0, int lane, int nmax,
                                           short (*__restrict__ scratch)[72],
                                           v2f (&row)[32]) {
    const int lm = lane & 15, quad = lane >> 4;

    // A-fragments for all 4 row-tiles (each lane: row waveRow0+rt*16+lm, k-slice quad*8..+8)
    s16x8 afr[4][4];
#pragma unroll
    for (int rt = 0; rt < 4; ++rt) {
        int arow = waveRow0 + rt * 16 + lm;
        if (arow >= nmax) arow = nmax - 1;
        const float* ap = rep + (size_t)arow * 128 + quad * 8;
#pragma unroll
        for (int kc = 0; kc < 4; ++kc) {
            const float4 x0 = *(const float4*)(ap + kc * 32);
            const float4 x1 = *(const float4*)(ap + kc * 32 + 4);
            s16x8 t;
            t[0] = f2bf(x0.x); t[1] = f2bf(x0.y); t[2] = f2bf(x0.z); t[3] = f2bf(x0.w);
            t[4] = f2bf(x1.x); t[5] = f2bf(x1.y); t[6] = f2bf(x1.z); t[7] = f2bf(x1.w);
            afr[rt][kc] = t;
        }
    }

    // ct-outer: only one column-tile's B-fragments live at a time
#pragma unroll
    for (int ct = 0; ct < 4; ++ct) {
        s16x8 bfr[4];
#pragma unroll
        for (int kc = 0; kc < 4; ++kc) {
            const float* wp = W + (size_t)(kc * 32 + quad * 8) * 64 + ct * 16 + lm;
            s16x8 t;
#pragma unroll
            for (int j = 0; j < 8; ++j) t[j] = f2bf(wp[j * 64]);
            bfr[kc] = t;
        }
#pragma unroll
        for (int rt = 0; rt < 4; ++rt) {
            f32x4 acc = (f32x4){0.f, 0.f, 0.f, 0.f};
#pragma unroll
            for (int kc = 0; kc < 4; ++kc)
                acc = __builtin_amdgcn_mfma_f32_16x16x32_bf16(
                    afr[rt][kc], bfr[kc], acc, 0, 0, 0);
            // scatter D (C-layout) to wave-private scratch, bf16
#pragma unroll
            for (int reg = 0; reg < 4; ++reg)
                scratch[rt * 16 + quad * 4 + reg][ct * 16 + lm] = f2bf(acc[reg]);
        }
    }

    // intra-wave exchange: all scatter writes drained, then gather own row.
    asm volatile("s_waitcnt lgkmcnt(0)" ::: "memory");
    const short* sr = scratch[lane];
#pragma unroll
    for (int c = 0; c < 32; ++c) {
        v2f t; t.x = bf2f(sr[2 * c]); t.y = bf2f(sr[2 * c + 1]);
        row[c] = t;
    }
    asm volatile("s_waitcnt lgkmcnt(0)" ::: "memory");  // reads done before scratch reuse
}

__global__ __launch_bounds__(256) void opening_critic_kernel(
    const float* __restrict__ rep, const float* __restrict__ pose,
    const float* __restrict__ opening,
    const float* __restrict__ kw1, const float* __restrict__ kg,  const float* __restrict__ kb,
    const float* __restrict__ kw2, const float* __restrict__ kb2,
    const float* __restrict__ qw1, const float* __restrict__ qg,  const float* __restrict__ qb,
    const float* __restrict__ qw2, const float* __restrict__ qb2,
    const float* __restrict__ vw1, const float* __restrict__ vg,  const float* __restrict__ vb,
    const float* __restrict__ vw2, const float* __restrict__ vb2,
    const float* __restrict__ aw1, const float* __restrict__ ag,  const float* __restrict__ ab,
    const float* __restrict__ aw2, const float* __restrict__ ab2,
    const float* __restrict__ rw1, const float* __restrict__ rg1, const float* __restrict__ rb1,
    const float* __restrict__ rw2, const float* __restrict__ rg2, const float* __restrict__ rb2,
    const float* __restrict__ rw3, const float* __restrict__ rb3,
    const float* __restrict__ gw1, const float* __restrict__ gg,  const float* __restrict__ gb,
    const float* __restrict__ gw2, const float* __restrict__ gb2,
    float* __restrict__ out, int n)
{
    // 36,864 B: 4 blocks/CU (was 69,632 B with keybuf -> 2 blocks/CU).
    // keybuf eliminated by reordering: key branch + attention head run FIRST,
    // leaving only att[8] (16 VGPRs) live across the residual MFMA phase.
    __shared__ short scratch[4][64][72];   // per-wave C->row transpose buffer

    const int tid  = threadIdx.x;
    const int wave = tid >> 6, lane = tid & 63;
    const int blockRow0 = blockIdx.x * 256;
    const int waveRow0  = blockRow0 + wave * 64;
    const int myrow     = blockRow0 + tid;            // == waveRow0 + lane
    const bool active   = (myrow < n);
    const int rowc      = active ? myrow : (n - 1);

    // per-row small inputs
    float pv[6];
#pragma unroll
    for (int i = 0; i < 6; ++i) pv[i] = pose[(size_t)rowc * 6 + i];
    const float ov = opening[rowc];

    // ---------------- Phase A: key branch (MFMA) ----------------
    v2f key[16];
    {
        v2f ka[32];
        mfma_phase(rep, kw1, waveRow0, lane, n, scratch[wave], ka);
        ln_relu2<32>(ka, kg, kb);
        mv2_bias<32, 16>(ka, kw2, kb2, key);
    }

    // query: 6 -> 16 -> 32
    v2f query[16];
    {
        v2f q1[8];
        const v2f* qw1_2 = (const v2f*)qw1;
#pragma unroll
        for (int j = 0; j < 8; ++j) q1[j] = bc2(0.f);
#pragma unroll
        for (int k = 0; k < 6; ++k) {
            const v2f xv = bc2(pv[k]);
#pragma unroll
            for (int j = 0; j < 8; ++j) q1[j] = pf(xv, qw1_2[k * 8 + j], q1[j]);
        }
        ln_relu2<8>(q1, qg, qb);
        mv2_bias<8, 16>(q1, qw2, qb2, query);
    }

    // value: 1 -> 16 -> 32
    v2f value[16];
    {
        v2f v1[8];
        const v2f* vw1_2 = (const v2f*)vw1;
        const v2f xo = bc2(ov);
#pragma unroll
        for (int j = 0; j < 8; ++j) v1[j] = xo * vw1_2[j];
        ln_relu2<8>(v1, vg, vb);
        mv2_bias<8, 16>(v1, vw2, vb2, value);
    }

    // softmax(query*key) * value
    v2f s[16];
#pragma unroll
    for (int j = 0; j < 16; ++j) s[j] = query[j] * key[j];
    float mx = -1e30f;
#pragma unroll
    for (int j = 0; j < 16; ++j) mx = fmaxf(mx, fmaxf(s[j].x, s[j].y));
    float sum = 0.f;
#pragma unroll
    for (int j = 0; j < 16; ++j) {
        s[j].x = __expf(s[j].x - mx);
        s[j].y = __expf(s[j].y - mx);
        sum += s[j].x + s[j].y;
    }
    const float inv = 1.0f / sum;
#pragma unroll
    for (int j = 0; j < 16; ++j) s[j] = s[j] * inv * value[j];

    // attention head: 32 -> 32 -> 16   (only att[8] survives past here)
    v2f att[8];
    {
        v2f a1[16];
        mv2<16, 16>(s, aw1, a1);
        ln_relu2<16>(a1, ag, ab);
        mv2_bias<16, 8>(a1, aw2, ab2, att);
    }

    // ---------------- Phase B: ra = rep @ rw1[0:128] (MFMA) + pose/open ----------------
    v2f residuals[8];
    {
        v2f ra[32];
        mfma_phase(rep, rw1, waveRow0, lane, n, scratch[wave], ra);
#pragma unroll
        for (int kk = 0; kk < 6; ++kk) {
            const v2f* w = (const v2f*)(rw1 + (128 + kk) * 64);
            const v2f xv = bc2(pv[kk]);
#pragma unroll
            for (int j = 0; j < 32; ++j) ra[j] = pf(xv, w[j], ra[j]);
        }
        {
            const v2f* w = (const v2f*)(rw1 + 134 * 64);
            const v2f xo = bc2(ov);
#pragma unroll
            for (int j = 0; j < 32; ++j) ra[j] = pf(xo, w[j], ra[j]);
        }
        ln_relu2<32>(ra, rg1, rb1);
        v2f h2[16];
        mv2<32, 16>(ra, rw2, h2);
        ln_relu2<16>(h2, rg2, rb2);
        mv2_bias<16, 8>(h2, rw3, rb3, residuals);
    }

    // get_value on concat([att, residuals]): 32 -> 16 -> 1
    float score;
    {
        v2f g1[8];
        const v2f* gw1_2 = (const v2f*)gw1;
#pragma unroll
        for (int j = 0; j < 8; ++j) g1[j] = bc2(0.f);
#pragma unroll
        for (int k2 = 0; k2 < 8; ++k2) {
            const v2f x0 = bc2(att[k2].x), x1 = bc2(att[k2].y);
#pragma unroll
            for (int j = 0; j < 8; ++j) {
                g1[j] = pf(x0, gw1_2[(2 * k2) * 8 + j], g1[j]);
                g1[j] = pf(x1, gw1_2[(2 * k2 + 1) * 8 + j], g1[j]);
            }
        }
#pragma unroll
        for (int k2 = 0; k2 < 8; ++k2) {
            const v2f x0 = bc2(residuals[k2].x), x1 = bc2(residuals[k2].y);
#pragma unroll
            for (int j = 0; j < 8; ++j) {
                g1[j] = pf(x0, gw1_2[(16 + 2 * k2) * 8 + j], g1[j]);
                g1[j] = pf(x1, gw1_2[(16 + 2 * k2 + 1) * 8 + j], g1[j]);
            }
        }
        ln_relu2<8>(g1, gg, gb);
        score = gb2[0];
        const v2f* gw2_2 = (const v2f*)gw2;
#pragma unroll
        for (int k = 0; k < 8; ++k) {
            score = fmaf(g1[k].x, gw2_2[k].x, score);
            score = fmaf(g1[k].y, gw2_2[k].y, score);
        }
    }

    if (active) out[myrow] = score;
}

extern "C" void kernel_launch(void* const* d_in, const int* in_sizes, int n_in,
                              void* d_out, int out_size, void* d_ws, size_t ws_size,
                              hipStream_t stream) {
    const float* rep     = (const float*)d_in[0];
    const float* pose    = (const float*)d_in[1];
    const float* opening = (const float*)d_in[2];
    const float* kw1 = (const float*)d_in[3];
    const float* kg  = (const float*)d_in[4];
    const float* kb  = (const float*)d_in[5];
    const float* kw2 = (const float*)d_in[6];
    const float* kb2 = (const float*)d_in[7];
    const float* qw1 = (const float*)d_in[8];
    const float* qg  = (const float*)d_in[9];
    const float* qb  = (const float*)d_in[10];
    const float* qw2 = (const float*)d_in[11];
    const float* qb2 = (const float*)d_in[12];
    const float* vw1 = (const float*)d_in[13];
    const float* vg  = (const float*)d_in[14];
    const float* vb  = (const float*)d_in[15];
    const float* vw2 = (const float*)d_in[16];
    const float* vb2 = (const float*)d_in[17];
    const float* aw1 = (const float*)d_in[18];
    const float* ag  = (const float*)d_in[19];
    const float* ab  = (const float*)d_in[20];
    const float* aw2 = (const float*)d_in[21];
    const float* ab2 = (const float*)d_in[22];
    const float* rw1 = (const float*)d_in[23];
    const float* rg1 = (const float*)d_in[24];
    const float* rb1 = (const float*)d_in[25];
    const float* rw2 = (const float*)d_in[26];
    const float* rg2 = (const float*)d_in[27];
    const float* rb2 = (const float*)d_in[28];
    const float* rw3 = (const float*)d_in[29];
    const float* rb3 = (const float*)d_in[30];
    const float* gw1 = (const float*)d_in[31];
    const float* gg  = (const float*)d_in[32];
    const float* gb  = (const float*)d_in[33];
    const float* gw2 = (const float*)d_in[34];
    const float* gb2 = (const float*)d_in[35];

    const int n = in_sizes[0] / 128;   // 524288 rows
    float* out = (float*)d_out;

    dim3 block(256);
    dim3 grid((n + 255) / 256);
    hipLaunchKernelGGL(opening_critic_kernel, grid, block, 0, stream,
                       rep, pose, opening,
                       kw1, kg, kb, kw2, kb2,
                       qw1, qg, qb, qw2, qb2,
                       vw1, vg, vb, vw2, vb2,
                       aw1, ag, ab, aw2, ab2,
                       rw1, rg1, rb1, rw2, rg2, rb2, rw3, rb3,
                       gw1, gg, gb, gw2, gb2,
                       out, n);
}

// Round 3
// 881.027 us; speedup vs baseline: 1.2327x; 1.2327x over previous
//
#include <hip/hip_runtime.h>
#include <math.h>

#define LN_EPS 1e-5f

typedef float v2f  __attribute__((ext_vector_type(2)));
typedef float f32x4 __attribute__((ext_vector_type(4)));
typedef short s16x8 __attribute__((ext_vector_type(8)));   // 8 bf16 in 4 VGPRs (guide §3)

__device__ __forceinline__ v2f pf(v2f a, v2f b, v2f c) {
    return __builtin_elementwise_fma(a, b, c);
}
__device__ __forceinline__ v2f bc2(float s) { v2f r; r.x = s; r.y = s; return r; }

// fp32 -> bf16 (RNE), bf16 -> fp32
__device__ __forceinline__ short f2bf(float f) {
    union { float f; unsigned u; } v; v.f = f;
    return (short)((v.u + 0x7fffu + ((v.u >> 16) & 1u)) >> 16);
}
__device__ __forceinline__ float bf2f(short s) {
    union { unsigned u; float f; } v; v.u = ((unsigned)(unsigned short)s) << 16;
    return v.f;
}

// LayerNorm over 2*D2 values held as v2f[D2], then *g+b, then ReLU (in place).
template<int D2>
__device__ __forceinline__ void ln_relu2(v2f (&v)[D2],
                                         const float* __restrict__ g,
                                         const float* __restrict__ b) {
    const float invD = 1.0f / (float)(2 * D2);
    float m = 0.f;
#pragma unroll
    for (int i = 0; i < D2; ++i) m += v[i].x + v[i].y;
    m *= invD;
    float var = 0.f;
#pragma unroll
    for (int i = 0; i < D2; ++i) {
        float dx = v[i].x - m, dy = v[i].y - m;
        var = fmaf(dx, dx, var);
        var = fmaf(dy, dy, var);
    }
    var *= invD;
    const float rs = rsqrtf(var + LN_EPS);
    const v2f* g2 = (const v2f*)g;
    const v2f* b2 = (const v2f*)b;
#pragma unroll
    for (int i = 0; i < D2; ++i) {
        v2f t = pf((v[i] - m) * rs, g2[i], b2[i]);
        v[i].x = fmaxf(t.x, 0.f);
        v[i].y = fmaxf(t.y, 0.f);
    }
}

// k-outer matvec (all OUT2 accumulators live). Use only when IN2 is small or
// the input array is about to die anyway.
template<int IN2, int OUT2>
__device__ __forceinline__ void mv2(const v2f (&x)[IN2],
                                    const float* __restrict__ W,
                                    v2f (&y)[OUT2]) {
    const v2f* W2 = (const v2f*)W;
#pragma unroll
    for (int j = 0; j < OUT2; ++j) y[j] = bc2(0.f);
#pragma unroll
    for (int k2 = 0; k2 < IN2; ++k2) {
        const v2f x0 = bc2(x[k2].x), x1 = bc2(x[k2].y);
#pragma unroll
        for (int j = 0; j < OUT2; ++j) {
            y[j] = pf(x0, W2[(2 * k2) * OUT2 + j], y[j]);
            y[j] = pf(x1, W2[(2 * k2 + 1) * OUT2 + j], y[j]);
        }
    }
}

template<int IN2, int OUT2>
__device__ __forceinline__ void mv2_bias(const v2f (&x)[IN2],
                                         const float* __restrict__ W,
                                         const float* __restrict__ bias,
                                         v2f (&y)[OUT2]) {
    const v2f* W2 = (const v2f*)W;
    const v2f* b2 = (const v2f*)bias;
#pragma unroll
    for (int j = 0; j < OUT2; ++j) y[j] = b2[j];
#pragma unroll
    for (int k2 = 0; k2 < IN2; ++k2) {
        const v2f x0 = bc2(x[k2].x), x1 = bc2(x[k2].y);
#pragma unroll
        for (int j = 0; j < OUT2; ++j) {
            y[j] = pf(x0, W2[(2 * k2) * OUT2 + j], y[j]);
            y[j] = pf(x1, W2[(2 * k2 + 1) * OUT2 + j], y[j]);
        }
    }
}

// j-outer matvec (+bias): only ONE v2f accumulator live at a time; per-output
// accumulation order (k ascending) is identical to mv2/mv2_bias -> bitwise-same.
template<int IN2, int OUT2>
__device__ __forceinline__ void mv2j_bias(const v2f (&x)[IN2],
                                          const float* __restrict__ W,
                                          const float* __restrict__ bias,
                                          v2f (&y)[OUT2]) {
    const v2f* W2 = (const v2f*)W;
    const v2f* b2 = (const v2f*)bias;
#pragma unroll
    for (int j = 0; j < OUT2; ++j) {
        v2f acc = b2[j];
#pragma unroll
        for (int k2 = 0; k2 < IN2; ++k2) {
            acc = pf(bc2(x[k2].x), W2[(2 * k2) * OUT2 + j], acc);
            acc = pf(bc2(x[k2].y), W2[(2 * k2 + 1) * OUT2 + j], acc);
        }
        y[j] = acc;
    }
}

template<int IN2, int OUT2>
__device__ __forceinline__ void mv2j(const v2f (&x)[IN2],
                                     const float* __restrict__ W,
                                     v2f (&y)[OUT2]) {
    const v2f* W2 = (const v2f*)W;
#pragma unroll
    for (int j = 0; j < OUT2; ++j) {
        v2f acc = bc2(0.f);
#pragma unroll
        for (int k2 = 0; k2 < IN2; ++k2) {
            acc = pf(bc2(x[k2].x), W2[(2 * k2) * OUT2 + j], acc);
            acc = pf(bc2(x[k2].y), W2[(2 * k2 + 1) * OUT2 + j], acc);
        }
        y[j] = acc;
    }
}

// One MFMA phase: row[0..63] (this lane's row of  X[128-wide slice] @ W[128,64])
// W row-major [128][64]. Result is PRE-LayerNorm, fp32 (via bf16 LDS round-trip).
// MFMA layouts (guide §3, HW-verified m89/m91/m120):
//   A[m=lane&15][k=quad*8+j]  B[k=quad*8+j][n=lane&15]  D: col=lane&15,row=quad*4+reg
// REGISTER-PRESSURE SHAPE (round-2 post-mortem): row-tiles processed in 2
// halves so only 2 A-fragments (32 VGPRs) are resident; B-fragments (16 VGPRs)
// reloaded per half from L1-hot weights. Loop peak ~55 live VGPRs.
// History: (256,4)+pressure~140 -> arch-64/agpr-64 split + 1.7 GB scratch spill
// (760us). Unpinned+pressure~156 -> compiler took 156 VGPR + ~100 AGPR slack ->
// 1 wave/SIMD (787us). This version: true peak ~120 -> pin (256,4) is safe.
__device__ __forceinline__ void mfma_phase(const float* __restrict__ rep,
                                           const float* __restrict__ W,
                                           int waveRow0, int lane, int nmax,
                                           short (*__restrict__ scratch)[72],
                                           v2f (&row)[32]) {
    const int lm = lane & 15, quad = lane >> 4;

#pragma unroll
    for (int rh = 0; rh < 2; ++rh) {          // row-tile halves: rts {2rh, 2rh+1}
        // A-fragments for this half (each lane: row waveRow0+rt*16+lm, k-slice quad*8..+8)
        s16x8 afr[2][4];
#pragma unroll
        for (int i = 0; i < 2; ++i) {
            int arow = waveRow0 + (2 * rh + i) * 16 + lm;
            if (arow >= nmax) arow = nmax - 1;
            const float* ap = rep + (size_t)arow * 128 + quad * 8;
#pragma unroll
            for (int kc = 0; kc < 4; ++kc) {
                const float4 x0 = *(const float4*)(ap + kc * 32);
                const float4 x1 = *(const float4*)(ap + kc * 32 + 4);
                s16x8 t;
                t[0] = f2bf(x0.x); t[1] = f2bf(x0.y); t[2] = f2bf(x0.z); t[3] = f2bf(x0.w);
                t[4] = f2bf(x1.x); t[5] = f2bf(x1.y); t[6] = f2bf(x1.z); t[7] = f2bf(x1.w);
                afr[i][kc] = t;
            }
        }

        // ct-outer: only one column-tile's B-fragments live at a time
#pragma unroll
        for (int ct = 0; ct < 4; ++ct) {
            s16x8 bfr[4];
#pragma unroll
            for (int kc = 0; kc < 4; ++kc) {
                const float* wp = W + (size_t)(kc * 32 + quad * 8) * 64 + ct * 16 + lm;
                s16x8 t;
#pragma unroll
                for (int j = 0; j < 8; ++j) t[j] = f2bf(wp[j * 64]);
                bfr[kc] = t;
            }
#pragma unroll
            for (int i = 0; i < 2; ++i) {
                f32x4 acc = (f32x4){0.f, 0.f, 0.f, 0.f};
#pragma unroll
                for (int kc = 0; kc < 4; ++kc)
                    acc = __builtin_amdgcn_mfma_f32_16x16x32_bf16(
                        afr[i][kc], bfr[kc], acc, 0, 0, 0);
                // scatter D (C-layout) to wave-private scratch, bf16
#pragma unroll
                for (int reg = 0; reg < 4; ++reg)
                    scratch[(2 * rh + i) * 16 + quad * 4 + reg][ct * 16 + lm] =
                        f2bf(acc[reg]);
            }
        }
    }

    // intra-wave exchange: all scatter writes drained, then gather own row.
    asm volatile("s_waitcnt lgkmcnt(0)" ::: "memory");
    const short* sr = scratch[lane];
#pragma unroll
    for (int c = 0; c < 32; ++c) {
        v2f t; t.x = bf2f(sr[2 * c]); t.y = bf2f(sr[2 * c + 1]);
        row[c] = t;
    }
    asm volatile("s_waitcnt lgkmcnt(0)" ::: "memory");  // reads done before scratch reuse
}

__global__ __launch_bounds__(256, 4) void opening_critic_kernel(
    const float* __restrict__ rep, const float* __restrict__ pose,
    const float* __restrict__ opening,
    const float* __restrict__ kw1, const float* __restrict__ kg,  const float* __restrict__ kb,
    const float* __restrict__ kw2, const float* __restrict__ kb2,
    const float* __restrict__ qw1, const float* __restrict__ qg,  const float* __restrict__ qb,
    const float* __restrict__ qw2, const float* __restrict__ qb2,
    const float* __restrict__ vw1, const float* __restrict__ vg,  const float* __restrict__ vb,
    const float* __restrict__ vw2, const float* __restrict__ vb2,
    const float* __restrict__ aw1, const float* __restrict__ ag,  const float* __restrict__ ab,
    const float* __restrict__ aw2, const float* __restrict__ ab2,
    const float* __restrict__ rw1, const float* __restrict__ rg1, const float* __restrict__ rb1,
    const float* __restrict__ rw2, const float* __restrict__ rg2, const float* __restrict__ rb2,
    const float* __restrict__ rw3, const float* __restrict__ rb3,
    const float* __restrict__ gw1, const float* __restrict__ gg,  const float* __restrict__ gb,
    const float* __restrict__ gw2, const float* __restrict__ gb2,
    float* __restrict__ out, int n)
{
    // 36,864 B: 4 blocks/CU. Together with VGPR<=128 (pin (256,4)) -> 16 waves/CU.
    __shared__ short scratch[4][64][72];   // per-wave C->row transpose buffer

    const int tid  = threadIdx.x;
    const int wave = tid >> 6, lane = tid & 63;
    const int blockRow0 = blockIdx.x * 256;
    const int waveRow0  = blockRow0 + wave * 64;
    const int myrow     = blockRow0 + tid;            // == waveRow0 + lane
    const bool active   = (myrow < n);
    const int rowc      = active ? myrow : (n - 1);

    // per-row small inputs
    float pv[6];
#pragma unroll
    for (int i = 0; i < 6; ++i) pv[i] = pose[(size_t)rowc * 6 + i];
    const float ov = opening[rowc];

    // ---------------- Phase A: key branch (MFMA) ----------------
    v2f key[16];
    {
        v2f ka[32];
        mfma_phase(rep, kw1, waveRow0, lane, n, scratch[wave], ka);
        ln_relu2<32>(ka, kg, kb);
        mv2j_bias<32, 16>(ka, kw2, kb2, key);    // j-outer: ka 64 + key fill 32 live
    }

    // query 6->16 (LN/ReLU), then FUSED j-outer query@qw2 * key -> s
    // (per-output accumulation order identical to the old mv2_bias -> bitwise-same)
    v2f s[16];
    {
        v2f q1[8];
        const v2f* qw1_2 = (const v2f*)qw1;
#pragma unroll
        for (int j = 0; j < 8; ++j) q1[j] = bc2(0.f);
#pragma unroll
        for (int k = 0; k < 6; ++k) {
            const v2f xv = bc2(pv[k]);
#pragma unroll
            for (int j = 0; j < 8; ++j) q1[j] = pf(xv, qw1_2[k * 8 + j], q1[j]);
        }
        ln_relu2<8>(q1, qg, qb);
        const v2f* W2 = (const v2f*)qw2;
        const v2f* b2 = (const v2f*)qb2;
#pragma unroll
        for (int j = 0; j < 16; ++j) {
            v2f acc = b2[j];
#pragma unroll
            for (int k2 = 0; k2 < 8; ++k2) {
                acc = pf(bc2(q1[k2].x), W2[(2 * k2) * 16 + j], acc);
                acc = pf(bc2(q1[k2].y), W2[(2 * k2 + 1) * 16 + j], acc);
            }
            s[j] = acc * key[j];                 // key[j] dies here
        }
    }

    // softmax over s (32 values)
    float mx = -1e30f;
#pragma unroll
    for (int j = 0; j < 16; ++j) mx = fmaxf(mx, fmaxf(s[j].x, s[j].y));
    float sum = 0.f;
#pragma unroll
    for (int j = 0; j < 16; ++j) {
        s[j].x = __expf(s[j].x - mx);
        s[j].y = __expf(s[j].y - mx);
        sum += s[j].x + s[j].y;
    }
    const float inv = 1.0f / sum;

    // value 1->16 (LN/ReLU), then FUSED j-outer value@vw2 applied to s:
    // s[j] = (s[j]*inv) * value[j]  — same op order as before.
    {
        v2f v1[8];
        const v2f* vw1_2 = (const v2f*)vw1;
        const v2f xo = bc2(ov);
#pragma unroll
        for (int j = 0; j < 8; ++j) v1[j] = xo * vw1_2[j];
        ln_relu2<8>(v1, vg, vb);
        const v2f* W2 = (const v2f*)vw2;
        const v2f* b2 = (const v2f*)vb2;
#pragma unroll
        for (int j = 0; j < 16; ++j) {
            v2f acc = b2[j];
#pragma unroll
            for (int k2 = 0; k2 < 8; ++k2) {
                acc = pf(bc2(v1[k2].x), W2[(2 * k2) * 16 + j], acc);
                acc = pf(bc2(v1[k2].y), W2[(2 * k2 + 1) * 16 + j], acc);
            }
            s[j] = s[j] * inv * acc;
        }
    }

    // attention head: 32 -> 32 -> 16   (only att[8] survives past here)
    v2f att[8];
    {
        v2f a1[16];
        mv2<16, 16>(s, aw1, a1);
        ln_relu2<16>(a1, ag, ab);
        mv2_bias<16, 8>(a1, aw2, ab2, att);
    }

    // ---------------- Phase B: ra = rep @ rw1[0:128] (MFMA) + pose/open ----------------
    v2f residuals[8];
    {
        v2f ra[32];
        mfma_phase(rep, rw1, waveRow0, lane, n, scratch[wave], ra);
#pragma unroll
        for (int kk = 0; kk < 6; ++kk) {
            const v2f* w = (const v2f*)(rw1 + (128 + kk) * 64);
            const v2f xv = bc2(pv[kk]);
#pragma unroll
            for (int j = 0; j < 32; ++j) ra[j] = pf(xv, w[j], ra[j]);
        }
        {
            const v2f* w = (const v2f*)(rw1 + 134 * 64);
            const v2f xo = bc2(ov);
#pragma unroll
            for (int j = 0; j < 32; ++j) ra[j] = pf(xo, w[j], ra[j]);
        }
        ln_relu2<32>(ra, rg1, rb1);
        v2f h2[16];
        mv2j<32, 16>(ra, rw2, h2);               // j-outer: ra 64 + h2 32 + att 16 peak
        ln_relu2<16>(h2, rg2, rb2);
        mv2_bias<16, 8>(h2, rw3, rb3, residuals);
    }

    // get_value on concat([att, residuals]): 32 -> 16 -> 1
    float score;
    {
        v2f g1[8];
        const v2f* gw1_2 = (const v2f*)gw1;
#pragma unroll
        for (int j = 0; j < 8; ++j) g1[j] = bc2(0.f);
#pragma unroll
        for (int k2 = 0; k2 < 8; ++k2) {
            const v2f x0 = bc2(att[k2].x), x1 = bc2(att[k2].y);
#pragma unroll
            for (int j = 0; j < 8; ++j) {
                g1[j] = pf(x0, gw1_2[(2 * k2) * 8 + j], g1[j]);
                g1[j] = pf(x1, gw1_2[(2 * k2 + 1) * 8 + j], g1[j]);
            }
        }
#pragma unroll
        for (int k2 = 0; k2 < 8; ++k2) {
            const v2f x0 = bc2(residuals[k2].x), x1 = bc2(residuals[k2].y);
#pragma unroll
            for (int j = 0; j < 8; ++j) {
                g1[j] = pf(x0, gw1_2[(16 + 2 * k2) * 8 + j], g1[j]);
                g1[j] = pf(x1, gw1_2[(16 + 2 * k2 + 1) * 8 + j], g1[j]);
            }
        }
        ln_relu2<8>(g1, gg, gb);
        score = gb2[0];
        const v2f* gw2_2 = (const v2f*)gw2;
#pragma unroll
        for (int k = 0; k < 8; ++k) {
            score = fmaf(g1[k].x, gw2_2[k].x, score);
            score = fmaf(g1[k].y, gw2_2[k].y, score);
        }
    }

    if (active) out[myrow] = score;
}

extern "C" void kernel_launch(void* const* d_in, const int* in_sizes, int n_in,
                              void* d_out, int out_size, void* d_ws, size_t ws_size,
                              hipStream_t stream) {
    const float* rep     = (const float*)d_in[0];
    const float* pose    = (const float*)d_in[1];
    const float* opening = (const float*)d_in[2];
    const float* kw1 = (const float*)d_in[3];
    const float* kg  = (const float*)d_in[4];
    const float* kb  = (const float*)d_in[5];
    const float* kw2 = (const float*)d_in[6];
    const float* kb2 = (const float*)d_in[7];
    const float* qw1 = (const float*)d_in[8];
    const float* qg  = (const float*)d_in[9];
    const float* qb  = (const float*)d_in[10];
    const float* qw2 = (const float*)d_in[11];
    const float* qb2 = (const float*)d_in[12];
    const float* vw1 = (const float*)d_in[13];
    const float* vg  = (const float*)d_in[14];
    const float* vb  = (const float*)d_in[15];
    const float* vw2 = (const float*)d_in[16];
    const float* vb2 = (const float*)d_in[17];
    const float* aw1 = (const float*)d_in[18];
    const float* ag  = (const float*)d_in[19];
    const float* ab  = (const float*)d_in[20];
    const float* aw2 = (const float*)d_in[21];
    const float* ab2 = (const float*)d_in[22];
    const float* rw1 = (const float*)d_in[23];
    const float* rg1 = (const float*)d_in[24];
    const float* rb1 = (const float*)d_in[25];
    const float* rw2 = (const float*)d_in[26];
    const float* rg2 = (const float*)d_in[27];
    const float* rb2 = (const float*)d_in[28];
    const float* rw3 = (const float*)d_in[29];
    const float* rb3 = (const float*)d_in[30];
    const float* gw1 = (const float*)d_in[31];
    const float* gg  = (const float*)d_in[32];
    const float* gb  = (const float*)d_in[33];
    const float* gw2 = (const float*)d_in[34];
    const float* gb2 = (const float*)d_in[35];

    const int n = in_sizes[0] / 128;   // 524288 rows
    float* out = (float*)d_out;

    dim3 block(256);
    dim3 grid((n + 255) / 256);
    hipLaunchKernelGGL(opening_critic_kernel, grid, block, 0, stream,
                       rep, pose, opening,
                       kw1, kg, kb, kw2, kb2,
                       qw1, qg, qb, qw2, qb2,
                       vw1, vg, vb, vw2, vb2,
                       aw1, ag, ab, aw2, ab2,
                       rw1, rg1, rb1, rw2, rg2, rb2, rw3, rb3,
                       gw1, gg, gb, gw2, gb2,
                       out, n);
}

// Round 4
// 731.249 us; speedup vs baseline: 1.4852x; 1.2048x over previous
//
#include <hip/hip_runtime.h>
#include <math.h>

#define LN_EPS 1e-5f

typedef float v2f  __attribute__((ext_vector_type(2)));
typedef float f32x4 __attribute__((ext_vector_type(4)));
typedef short s16x8 __attribute__((ext_vector_type(8)));   // 8 bf16 in 4 VGPRs (guide §3)

__device__ __forceinline__ v2f pf(v2f a, v2f b, v2f c) {
    return __builtin_elementwise_fma(a, b, c);
}
__device__ __forceinline__ v2f bc2(float s) { v2f r; r.x = s; r.y = s; return r; }

// fp32 -> bf16 (RNE), bf16 -> fp32
__device__ __forceinline__ short f2bf(float f) {
    union { float f; unsigned u; } v; v.f = f;
    return (short)((v.u + 0x7fffu + ((v.u >> 16) & 1u)) >> 16);
}
__device__ __forceinline__ float bf2f(short s) {
    union { unsigned u; float f; } v; v.u = ((unsigned)(unsigned short)s) << 16;
    return v.f;
}

// LayerNorm over 2*D2 values held as v2f[D2], then *g+b, then ReLU (in place).
template<int D2>
__device__ __forceinline__ void ln_relu2(v2f (&v)[D2],
                                         const float* __restrict__ g,
                                         const float* __restrict__ b) {
    const float invD = 1.0f / (float)(2 * D2);
    float m = 0.f;
#pragma unroll
    for (int i = 0; i < D2; ++i) m += v[i].x + v[i].y;
    m *= invD;
    float var = 0.f;
#pragma unroll
    for (int i = 0; i < D2; ++i) {
        float dx = v[i].x - m, dy = v[i].y - m;
        var = fmaf(dx, dx, var);
        var = fmaf(dy, dy, var);
    }
    var *= invD;
    const float rs = rsqrtf(var + LN_EPS);
    const v2f* g2 = (const v2f*)g;
    const v2f* b2 = (const v2f*)b;
#pragma unroll
    for (int i = 0; i < D2; ++i) {
        v2f t = pf((v[i] - m) * rs, g2[i], b2[i]);
        v[i].x = fmaxf(t.x, 0.f);
        v[i].y = fmaxf(t.y, 0.f);
    }
}

// k-outer matvec (all OUT2 accumulators live).
template<int IN2, int OUT2>
__device__ __forceinline__ void mv2(const v2f (&x)[IN2],
                                    const float* __restrict__ W,
                                    v2f (&y)[OUT2]) {
    const v2f* W2 = (const v2f*)W;
#pragma unroll
    for (int j = 0; j < OUT2; ++j) y[j] = bc2(0.f);
#pragma unroll
    for (int k2 = 0; k2 < IN2; ++k2) {
        const v2f x0 = bc2(x[k2].x), x1 = bc2(x[k2].y);
#pragma unroll
        for (int j = 0; j < OUT2; ++j) {
            y[j] = pf(x0, W2[(2 * k2) * OUT2 + j], y[j]);
            y[j] = pf(x1, W2[(2 * k2 + 1) * OUT2 + j], y[j]);
        }
    }
}

template<int IN2, int OUT2>
__device__ __forceinline__ void mv2_bias(const v2f (&x)[IN2],
                                         const float* __restrict__ W,
                                         const float* __restrict__ bias,
                                         v2f (&y)[OUT2]) {
    const v2f* W2 = (const v2f*)W;
    const v2f* b2 = (const v2f*)bias;
#pragma unroll
    for (int j = 0; j < OUT2; ++j) y[j] = b2[j];
#pragma unroll
    for (int k2 = 0; k2 < IN2; ++k2) {
        const v2f x0 = bc2(x[k2].x), x1 = bc2(x[k2].y);
#pragma unroll
        for (int j = 0; j < OUT2; ++j) {
            y[j] = pf(x0, W2[(2 * k2) * OUT2 + j], y[j]);
            y[j] = pf(x1, W2[(2 * k2 + 1) * OUT2 + j], y[j]);
        }
    }
}

// j-outer matvec (+bias): one accumulator live at a time; per-output
// accumulation order (k ascending) identical to mv2/mv2_bias -> bitwise-same.
template<int IN2, int OUT2>
__device__ __forceinline__ void mv2j_bias(const v2f (&x)[IN2],
                                          const float* __restrict__ W,
                                          const float* __restrict__ bias,
                                          v2f (&y)[OUT2]) {
    const v2f* W2 = (const v2f*)W;
    const v2f* b2 = (const v2f*)bias;
#pragma unroll
    for (int j = 0; j < OUT2; ++j) {
        v2f acc = b2[j];
#pragma unroll
        for (int k2 = 0; k2 < IN2; ++k2) {
            acc = pf(bc2(x[k2].x), W2[(2 * k2) * OUT2 + j], acc);
            acc = pf(bc2(x[k2].y), W2[(2 * k2 + 1) * OUT2 + j], acc);
        }
        y[j] = acc;
    }
}

template<int IN2, int OUT2>
__device__ __forceinline__ void mv2j(const v2f (&x)[IN2],
                                     const float* __restrict__ W,
                                     v2f (&y)[OUT2]) {
    const v2f* W2 = (const v2f*)W;
#pragma unroll
    for (int j = 0; j < OUT2; ++j) {
        v2f acc = bc2(0.f);
#pragma unroll
        for (int k2 = 0; k2 < IN2; ++k2) {
            acc = pf(bc2(x[k2].x), W2[(2 * k2) * OUT2 + j], acc);
            acc = pf(bc2(x[k2].y), W2[(2 * k2 + 1) * OUT2 + j], acc);
        }
        y[j] = acc;
    }
}

// ============================================================================
// STAGE KERNEL — MFMA only. Computes rep@kw1 and rep@rw1[0:128] (pre-LN, bf16)
// and writes them row-major to workspace. This is the ONLY kernel with MFMA,
// so the allocator's 64-AGPR reservation (rounds 1/3 post-mortem: any pin with
// MFMA present splits the budget arch=64/agpr=64 and spills) lives here, where
// the live set (afr 64 + bfr 16 + acc + addr ~= 110) fits a 128/128 split
// under (256,2).
// MFMA layouts (guide §3, HW-verified m89/m91/m120):
//   A[m=lane&15][k=quad*8+j]  B[k=quad*8+j][n=lane&15]  D: col=lane&15,row=quad*4+reg
// ============================================================================
__global__ __launch_bounds__(256, 2) void opening_critic_stage(
    const float* __restrict__ rep,
    const float* __restrict__ kw1, const float* __restrict__ rw1,
    short* __restrict__ o1, short* __restrict__ o2, int nloc)
{
    __shared__ __align__(16) short scratch[4][64][72];   // per-wave C->row transpose

    const int tid  = threadIdx.x;
    const int wave = tid >> 6, lane = tid & 63;
    const int waveRow0 = blockIdx.x * 256 + wave * 64;
    const int myrow    = waveRow0 + lane;
    const int lm = lane & 15, quad = lane >> 4;

    // A-fragments resident (loaded once, used for BOTH weight matrices)
    s16x8 afr[4][4];
#pragma unroll
    for (int rt = 0; rt < 4; ++rt) {
        int arow = waveRow0 + rt * 16 + lm;
        if (arow >= nloc) arow = nloc - 1;
        const float* ap = rep + (size_t)arow * 128 + quad * 8;
#pragma unroll
        for (int kc = 0; kc < 4; ++kc) {
            const float4 x0 = *(const float4*)(ap + kc * 32);
            const float4 x1 = *(const float4*)(ap + kc * 32 + 4);
            s16x8 t;
            t[0] = f2bf(x0.x); t[1] = f2bf(x0.y); t[2] = f2bf(x0.z); t[3] = f2bf(x0.w);
            t[4] = f2bf(x1.x); t[5] = f2bf(x1.y); t[6] = f2bf(x1.z); t[7] = f2bf(x1.w);
            afr[rt][kc] = t;
        }
    }

#pragma unroll 1
    for (int w = 0; w < 2; ++w) {
        const float* __restrict__ W = w ? rw1 : kw1;
        short* __restrict__ O = w ? o2 : o1;

        // ct-outer: one column-tile's B-fragments live at a time
#pragma unroll
        for (int ct = 0; ct < 4; ++ct) {
            s16x8 bfr[4];
#pragma unroll
            for (int kc = 0; kc < 4; ++kc) {
                const float* wp = W + (size_t)(kc * 32 + quad * 8) * 64 + ct * 16 + lm;
                s16x8 t;
#pragma unroll
                for (int j = 0; j < 8; ++j) t[j] = f2bf(wp[j * 64]);
                bfr[kc] = t;
            }
#pragma unroll
            for (int rt = 0; rt < 4; ++rt) {
                f32x4 acc = (f32x4){0.f, 0.f, 0.f, 0.f};
#pragma unroll
                for (int kc = 0; kc < 4; ++kc)
                    acc = __builtin_amdgcn_mfma_f32_16x16x32_bf16(
                        afr[rt][kc], bfr[kc], acc, 0, 0, 0);
                // scatter D (C-layout) to wave-private scratch, bf16
#pragma unroll
                for (int reg = 0; reg < 4; ++reg)
                    scratch[wave][rt * 16 + quad * 4 + reg][ct * 16 + lm] = f2bf(acc[reg]);
            }
        }

        // intra-wave exchange: scatter writes drained, gather own row, store.
        asm volatile("s_waitcnt lgkmcnt(0)" ::: "memory");
        if (myrow < nloc) {
            const s16x8* sr = (const s16x8*)scratch[wave][lane];
            s16x8* dst = (s16x8*)(O + (size_t)myrow * 64);
#pragma unroll
            for (int i = 0; i < 8; ++i) dst[i] = sr[i];   // 8 x (ds_read_b128 + dwordx4 store)
        }
        asm volatile("s_waitcnt lgkmcnt(0)" ::: "memory");  // reads done before scratch reuse
    }
}

// ============================================================================
// TAIL KERNEL — pure VALU. NO MFMA -> zero AGPR demand -> (256,4) pin grants
// the full 128 arch VGPRs (peak live ~120). NO LDS. 16 waves/CU.
// Reads the bf16 staged rows (bitwise-identical values to the old in-kernel
// scratch round-trip) and runs the round-3 fused tail.
// ============================================================================
__global__ __launch_bounds__(256, 4) void opening_critic_tail(
    const short* __restrict__ o1, const short* __restrict__ o2,
    const float* __restrict__ pose, const float* __restrict__ opening,
    const float* __restrict__ kg,  const float* __restrict__ kb,
    const float* __restrict__ kw2, const float* __restrict__ kb2,
    const float* __restrict__ qw1, const float* __restrict__ qg,  const float* __restrict__ qb,
    const float* __restrict__ qw2, const float* __restrict__ qb2,
    const float* __restrict__ vw1, const float* __restrict__ vg,  const float* __restrict__ vb,
    const float* __restrict__ vw2, const float* __restrict__ vb2,
    const float* __restrict__ aw1, const float* __restrict__ ag,  const float* __restrict__ ab,
    const float* __restrict__ aw2, const float* __restrict__ ab2,
    const float* __restrict__ rw1, const float* __restrict__ rg1, const float* __restrict__ rb1,
    const float* __restrict__ rw2, const float* __restrict__ rg2, const float* __restrict__ rb2,
    const float* __restrict__ rw3, const float* __restrict__ rb3,
    const float* __restrict__ gw1, const float* __restrict__ gg,  const float* __restrict__ gb,
    const float* __restrict__ gw2, const float* __restrict__ gb2,
    float* __restrict__ out, int nloc)
{
    const int myrow = blockIdx.x * 256 + threadIdx.x;
    if (myrow >= nloc) return;   // no barriers/LDS -> early exit is safe

    float pv[6];
#pragma unroll
    for (int i = 0; i < 6; ++i) pv[i] = pose[(size_t)myrow * 6 + i];
    const float ov = opening[myrow];

    // ---------------- key branch from staged row ----------------
    v2f key[16];
    {
        v2f ka[32];
        const s16x8* r1 = (const s16x8*)(o1 + (size_t)myrow * 64);
#pragma unroll
        for (int i = 0; i < 8; ++i) {
            const s16x8 t = r1[i];
#pragma unroll
            for (int j = 0; j < 4; ++j) {
                v2f u; u.x = bf2f(t[2 * j]); u.y = bf2f(t[2 * j + 1]);
                ka[i * 4 + j] = u;
            }
        }
        ln_relu2<32>(ka, kg, kb);
        mv2j_bias<32, 16>(ka, kw2, kb2, key);   // j-outer: ka 64 + key fill
    }

    // query 6->16 (LN/ReLU), then FUSED j-outer query@qw2 * key -> s
    v2f s[16];
    {
        v2f q1[8];
        const v2f* qw1_2 = (const v2f*)qw1;
#pragma unroll
        for (int j = 0; j < 8; ++j) q1[j] = bc2(0.f);
#pragma unroll
        for (int k = 0; k < 6; ++k) {
            const v2f xv = bc2(pv[k]);
#pragma unroll
            for (int j = 0; j < 8; ++j) q1[j] = pf(xv, qw1_2[k * 8 + j], q1[j]);
        }
        ln_relu2<8>(q1, qg, qb);
        const v2f* W2 = (const v2f*)qw2;
        const v2f* b2 = (const v2f*)qb2;
#pragma unroll
        for (int j = 0; j < 16; ++j) {
            v2f acc = b2[j];
#pragma unroll
            for (int k2 = 0; k2 < 8; ++k2) {
                acc = pf(bc2(q1[k2].x), W2[(2 * k2) * 16 + j], acc);
                acc = pf(bc2(q1[k2].y), W2[(2 * k2 + 1) * 16 + j], acc);
            }
            s[j] = acc * key[j];                 // key[j] dies here
        }
    }

    // softmax over s (32 values)
    float mx = -1e30f;
#pragma unroll
    for (int j = 0; j < 16; ++j) mx = fmaxf(mx, fmaxf(s[j].x, s[j].y));
    float sum = 0.f;
#pragma unroll
    for (int j = 0; j < 16; ++j) {
        s[j].x = __expf(s[j].x - mx);
        s[j].y = __expf(s[j].y - mx);
        sum += s[j].x + s[j].y;
    }
    const float inv = 1.0f / sum;

    // value 1->16 (LN/ReLU), FUSED j-outer value@vw2 applied to s
    {
        v2f v1[8];
        const v2f* vw1_2 = (const v2f*)vw1;
        const v2f xo = bc2(ov);
#pragma unroll
        for (int j = 0; j < 8; ++j) v1[j] = xo * vw1_2[j];
        ln_relu2<8>(v1, vg, vb);
        const v2f* W2 = (const v2f*)vw2;
        const v2f* b2 = (const v2f*)vb2;
#pragma unroll
        for (int j = 0; j < 16; ++j) {
            v2f acc = b2[j];
#pragma unroll
            for (int k2 = 0; k2 < 8; ++k2) {
                acc = pf(bc2(v1[k2].x), W2[(2 * k2) * 16 + j], acc);
                acc = pf(bc2(v1[k2].y), W2[(2 * k2 + 1) * 16 + j], acc);
            }
            s[j] = s[j] * inv * acc;
        }
    }

    // attention head: 32 -> 32 -> 16   (only att[8] survives past here)
    v2f att[8];
    {
        v2f a1[16];
        mv2<16, 16>(s, aw1, a1);
        ln_relu2<16>(a1, ag, ab);
        mv2_bias<16, 8>(a1, aw2, ab2, att);
    }

    // ---------------- residual branch from staged row ----------------
    v2f residuals[8];
    {
        v2f ra[32];
        const s16x8* r2 = (const s16x8*)(o2 + (size_t)myrow * 64);
#pragma unroll
        for (int i = 0; i < 8; ++i) {
            const s16x8 t = r2[i];
#pragma unroll
            for (int j = 0; j < 4; ++j) {
                v2f u; u.x = bf2f(t[2 * j]); u.y = bf2f(t[2 * j + 1]);
                ra[i * 4 + j] = u;
            }
        }
#pragma unroll
        for (int kk = 0; kk < 6; ++kk) {
            const v2f* w = (const v2f*)(rw1 + (128 + kk) * 64);
            const v2f xv = bc2(pv[kk]);
#pragma unroll
            for (int j = 0; j < 32; ++j) ra[j] = pf(xv, w[j], ra[j]);
        }
        {
            const v2f* w = (const v2f*)(rw1 + 134 * 64);
            const v2f xo = bc2(ov);
#pragma unroll
            for (int j = 0; j < 32; ++j) ra[j] = pf(xo, w[j], ra[j]);
        }
        ln_relu2<32>(ra, rg1, rb1);
        v2f h2[16];
        mv2j<32, 16>(ra, rw2, h2);               // j-outer: ra 64 + h2 32 + att 16 peak
        ln_relu2<16>(h2, rg2, rb2);
        mv2_bias<16, 8>(h2, rw3, rb3, residuals);
    }

    // get_value on concat([att, residuals]): 32 -> 16 -> 1
    float score;
    {
        v2f g1[8];
        const v2f* gw1_2 = (const v2f*)gw1;
#pragma unroll
        for (int j = 0; j < 8; ++j) g1[j] = bc2(0.f);
#pragma unroll
        for (int k2 = 0; k2 < 8; ++k2) {
            const v2f x0 = bc2(att[k2].x), x1 = bc2(att[k2].y);
#pragma unroll
            for (int j = 0; j < 8; ++j) {
                g1[j] = pf(x0, gw1_2[(2 * k2) * 8 + j], g1[j]);
                g1[j] = pf(x1, gw1_2[(2 * k2 + 1) * 8 + j], g1[j]);
            }
        }
#pragma unroll
        for (int k2 = 0; k2 < 8; ++k2) {
            const v2f x0 = bc2(residuals[k2].x), x1 = bc2(residuals[k2].y);
#pragma unroll
            for (int j = 0; j < 8; ++j) {
                g1[j] = pf(x0, gw1_2[(16 + 2 * k2) * 8 + j], g1[j]);
                g1[j] = pf(x1, gw1_2[(16 + 2 * k2 + 1) * 8 + j], g1[j]);
            }
        }
        ln_relu2<8>(g1, gg, gb);
        score = gb2[0];
        const v2f* gw2_2 = (const v2f*)gw2;
#pragma unroll
        for (int k = 0; k < 8; ++k) {
            score = fmaf(g1[k].x, gw2_2[k].x, score);
            score = fmaf(g1[k].y, gw2_2[k].y, score);
        }
    }

    out[myrow] = score;
}

extern "C" void kernel_launch(void* const* d_in, const int* in_sizes, int n_in,
                              void* d_out, int out_size, void* d_ws, size_t ws_size,
                              hipStream_t stream) {
    const float* rep     = (const float*)d_in[0];
    const float* pose    = (const float*)d_in[1];
    const float* opening = (const float*)d_in[2];
    const float* kw1 = (const float*)d_in[3];
    const float* kg  = (const float*)d_in[4];
    const float* kb  = (const float*)d_in[5];
    const float* kw2 = (const float*)d_in[6];
    const float* kb2 = (const float*)d_in[7];
    const float* qw1 = (const float*)d_in[8];
    const float* qg  = (const float*)d_in[9];
    const float* qb  = (const float*)d_in[10];
    const float* qw2 = (const float*)d_in[11];
    const float* qb2 = (const float*)d_in[12];
    const float* vw1 = (const float*)d_in[13];
    const float* vg  = (const float*)d_in[14];
    const float* vb  = (const float*)d_in[15];
    const float* vw2 = (const float*)d_in[16];
    const float* vb2 = (const float*)d_in[17];
    const float* aw1 = (const float*)d_in[18];
    const float* ag  = (const float*)d_in[19];
    const float* ab  = (const float*)d_in[20];
    const float* aw2 = (const float*)d_in[21];
    const float* ab2 = (const float*)d_in[22];
    const float* rw1 = (const float*)d_in[23];
    const float* rg1 = (const float*)d_in[24];
    const float* rb1 = (const float*)d_in[25];
    const float* rw2 = (const float*)d_in[26];
    const float* rg2 = (const float*)d_in[27];
    const float* rb2 = (const float*)d_in[28];
    const float* rw3 = (const float*)d_in[29];
    const float* rb3 = (const float*)d_in[30];
    const float* gw1 = (const float*)d_in[31];
    const float* gg  = (const float*)d_in[32];
    const float* gb  = (const float*)d_in[33];
    const float* gw2 = (const float*)d_in[34];
    const float* gb2 = (const float*)d_in[35];

    const int n = in_sizes[0] / 128;   // 524288 rows
    float* out = (float*)d_out;

    // Workspace: 2 bf16 rows of 64 per sample = 256 B/row. Chunk if ws is small.
    const size_t perRowBytes = 2 * 64 * sizeof(short);
    const long long cap = (long long)(ws_size / perRowBytes);
    int C;
    if (cap >= (long long)n) C = n;
    else {
        C = (int)((cap / 256) * 256);
        if (C < 256) C = 256;   // workspace is expected to be far larger than 64 KB
    }
    short* o1 = (short*)d_ws;
    short* o2 = o1 + (size_t)C * 64;

    dim3 block(256);
    for (int r0 = 0; r0 < n; r0 += C) {
        const int nloc = (n - r0 < C) ? (n - r0) : C;
        dim3 grid((nloc + 255) / 256);
        hipLaunchKernelGGL(opening_critic_stage, grid, block, 0, stream,
                           rep + (size_t)r0 * 128, kw1, rw1, o1, o2, nloc);
        hipLaunchKernelGGL(opening_critic_tail, grid, block, 0, stream,
                           o1, o2, pose + (size_t)r0 * 6, opening + r0,
                           kg, kb, kw2, kb2,
                           qw1, qg, qb, qw2, qb2,
                           vw1, vg, vb, vw2, vb2,
                           aw1, ag, ab, aw2, ab2,
                           rw1, rg1, rb1, rw2, rg2, rb2, rw3, rb3,
                           gw1, gg, gb, gw2, gb2,
                           out + r0, nloc);
    }
}